// Round 11
// baseline (133.511 us; speedup 1.0000x reference)
//
#include <hip/hip_runtime.h>

#define Bsz  4
#define Nseq 2048
#define Hn   16
#define Dh   64
#define BH   (Bsz*Hn)
#define NT64 (Nseq/64)
#define NT32 (Nseq/32)

#define AS1 __attribute__((address_space(1)))
#define AS3 __attribute__((address_space(3)))

typedef __attribute__((ext_vector_type(8))) short bf16x8;
typedef __attribute__((ext_vector_type(16))) float f32x16;
typedef __attribute__((ext_vector_type(4))) float f32x4;
typedef __attribute__((ext_vector_type(2))) float f32x2;
typedef __attribute__((ext_vector_type(4))) unsigned short u16x4;

#define MFMA32 __builtin_amdgcn_mfma_f32_32x32x16_bf16

static __device__ __forceinline__ unsigned short f2bf(float f) {
    unsigned u = __float_as_uint(f);
    u = (u + 0x7fffu + ((u >> 16) & 1u)) >> 16;
    return (unsigned short)u;
}
static __device__ __forceinline__ float bf2f(unsigned short s) {
    return __uint_as_float((unsigned)s << 16);
}
static __device__ __forceinline__ unsigned cvt_pk_bf16(float lo, float hi) {
    unsigned r;
    asm("v_cvt_pk_bf16_f32 %0, %1, %2" : "=v"(r) : "v"(lo), "v"(hi));
    return r;
}
static __device__ __forceinline__ void swap32(unsigned &a, unsigned &b) {
    asm("v_permlane32_swap_b32 %0, %1" : "+v"(a), "+v"(b));
}
static __device__ __forceinline__ float exp2v(float x) {
    float r;
    asm("v_exp_f32 %0, %1" : "=v"(r) : "v"(x));
    return r;
}
static __device__ __forceinline__ f32x2 pk_add(f32x2 a, f32x2 b) {
    f32x2 d;
    asm("v_pk_add_f32 %0, %1, %2" : "=v"(d) : "v"(a), "v"(b));
    return d;
}

// ---------------------------------------------------------------------------
// Kernel 0: weight prep. Wt_hi/lo[m][h][o][d] bf16 split of W[m][h][d][o].
// (unchanged, validated)
// ---------------------------------------------------------------------------
__global__ __launch_bounds__(256) void wprep_kernel(
    const float* __restrict__ Wq, const float* __restrict__ Wk,
    const float* __restrict__ Wv,
    unsigned short* __restrict__ gWtH, unsigned short* __restrict__ gWtL)
{
    __shared__ float ws[64][65];
    const int mh = blockIdx.x;          // m*16 + h
    const int m = mh >> 4, h = mh & 15;
    const int tid = threadIdx.x;
    const float* W = (m == 0 ? Wq : (m == 1 ? Wk : Wv)) + h * 4096;

    for (int c = tid; c < 1024; c += 256) {
        int row = c >> 4, col = (c & 15) * 4;
        *(f32x4*)&ws[row][col] = *(const f32x4*)&W[row * 64 + col];
    }
    __syncthreads();

    const int o = tid >> 2, dblk = (tid & 3) * 16;
    size_t base = ((size_t)mh * 64 + o) * 64 + dblk;
#pragma unroll
    for (int i4 = 0; i4 < 4; ++i4) {
        u16x4 vh, vl;
#pragma unroll
        for (int j = 0; j < 4; ++j) {
            float v = ws[dblk + i4 * 4 + j][o];
            unsigned short hh = f2bf(v);
            vh[j] = hh;
            vl[j] = f2bf(v - bf2f(hh));
        }
        *(u16x4*)&gWtH[base + i4 * 4] = vh;
        *(u16x4*)&gWtL[base + i4 * 4] = vl;
    }
}

// ---------------------------------------------------------------------------
// Kernel 1: QKV projections via bf16 MFMA with hi/lo split precision.
// (unchanged from round 10, validated absmax 9.77e-4)
//   gQ : [BH][N][64]                pre-scaled by log2(e)/32
//   gK : [BH][N][64]                16B-chunk swizzle: chunk ^= (n&7)
//   gVt: [BH][NT32][64 o][32 n]     per-32-key tile transposed,
//                                   8-key chunk swizzle: chunk ^= (o>>2)&3
// ---------------------------------------------------------------------------
__global__ __launch_bounds__(256) void proj_kernel(
    const float* __restrict__ x,
    const unsigned short* __restrict__ gWtH, const unsigned short* __restrict__ gWtL,
    const float* __restrict__ bq, const float* __restrict__ bk,
    const float* __restrict__ bv,
    unsigned short* __restrict__ gQ, unsigned short* __restrict__ gK,
    unsigned short* __restrict__ gVt)
{
    __shared__ unsigned short st[64][72];   // bounce tile (+8 pad: 2-way free)

    const int bh = blockIdx.x, h = bh & (Hn - 1), b = bh >> 4;
    const int n0 = blockIdx.y * 64;
    const int tid = threadIdx.x;
    const int w = tid >> 6, lane = tid & 63, l31 = lane & 31, l5 = lane >> 5;
    const int qi = w >> 1, oj = w & 1;

    const int nrow = n0 + qi * 32 + l31;
    const float* xrow = x + (((size_t)b * Nseq + nrow) * Hn + h) * Dh;

    bf16x8 xh[4], xl[4];
#pragma unroll
    for (int ks = 0; ks < 4; ++ks) {
        f32x4 v0 = *(const f32x4*)&xrow[ks * 16 + l5 * 8];
        f32x4 v1 = *(const f32x4*)&xrow[ks * 16 + l5 * 8 + 4];
#pragma unroll
        for (int e = 0; e < 4; ++e) {
            unsigned short h0 = f2bf(v0[e]);
            xh[ks][e] = (short)h0;
            xl[ks][e] = (short)f2bf(v0[e] - bf2f(h0));
            unsigned short h1 = f2bf(v1[e]);
            xh[ks][4 + e] = (short)h1;
            xl[ks][4 + e] = (short)f2bf(v1[e] - bf2f(h1));
        }
    }

    const int o = oj * 32 + l31;

    f32x16 acc[3] = {};
#pragma unroll
    for (int m = 0; m < 3; ++m) {
        const unsigned short* WH = gWtH + (((size_t)m * 16 + h) * 64 + o) * 64;
        const unsigned short* WL = gWtL + (((size_t)m * 16 + h) * 64 + o) * 64;
#pragma unroll
        for (int ks = 0; ks < 4; ++ks) {
            bf16x8 wh = *(const bf16x8*)&WH[ks * 16 + l5 * 8];
            bf16x8 wl = *(const bf16x8*)&WL[ks * 16 + l5 * 8];
            if (m < 2) {
                acc[m] = MFMA32(xh[ks], wh, acc[m], 0, 0, 0);
                acc[m] = MFMA32(xl[ks], wh, acc[m], 0, 0, 0);
                acc[m] = MFMA32(xh[ks], wl, acc[m], 0, 0, 0);
            } else {               // V transposed: A = W^T, B = x^T
                acc[2] = MFMA32(wh, xh[ks], acc[2], 0, 0, 0);
                acc[2] = MFMA32(wl, xh[ks], acc[2], 0, 0, 0);
                acc[2] = MFMA32(wh, xl[ks], acc[2], 0, 0, 0);
            }
        }
    }

    const size_t gbase = (size_t)bh * Nseq + n0;

    // ---- Q: bounce + coalesced store ----
    {
        float bias = bq[h * 64 + o];
#pragma unroll
        for (int r = 0; r < 16; ++r) {
            int nl = (r & 3) + 8 * (r >> 2) + 4 * l5;
            st[qi * 32 + nl][o] = f2bf((acc[0][r] + bias) * 0.0450842200f);
        }
    }
    __syncthreads();
#pragma unroll
    for (int i = 0; i < 2; ++i) {
        int c = i * 256 + tid;
        int row = c >> 3, ch = c & 7;
        bf16x8 v = *(const bf16x8*)&st[row][ch * 8];
        *(bf16x8*)&gQ[(gbase + row) * Dh + ch * 8] = v;
    }
    __syncthreads();

    // ---- K: bounce + coalesced store at swizzled chunk position ----
    {
        float bias = bk[h * 64 + o];
#pragma unroll
        for (int r = 0; r < 16; ++r) {
            int nl = (r & 3) + 8 * (r >> 2) + 4 * l5;
            st[qi * 32 + nl][o] = f2bf(acc[1][r] + bias);
        }
    }
    __syncthreads();
#pragma unroll
    for (int i = 0; i < 2; ++i) {
        int c = i * 256 + tid;
        int row = c >> 3, ch = c & 7;
        bf16x8 v = *(const bf16x8*)&st[row][ch * 8];
        *(bf16x8*)&gK[(gbase + row) * Dh + ((ch ^ (row & 7)) * 8)] = v;
    }
    __syncthreads();

    // ---- V: bounce transposed [o][n] + coalesced store ----
    {
#pragma unroll
        for (int r = 0; r < 16; ++r) {
            int ol = (r & 3) + 8 * (r >> 2) + 4 * l5;
            int ov = oj * 32 + ol;
            st[ov][qi * 32 + l31] = f2bf(acc[2][r] + bv[h * 64 + ov]);
        }
    }
    __syncthreads();
#pragma unroll
    for (int i = 0; i < 2; ++i) {
        int c = i * 256 + tid;
        int orow = c >> 3, ch = c & 7;
        int tile = ch >> 2, c4 = ch & 3;
        bf16x8 v = *(const bf16x8*)&st[orow][ch * 8];
        *(bf16x8*)&gVt[((size_t)(bh * NT32 + (n0 >> 5) + tile)) * 2048 +
                       orow * 32 + ((c4 ^ ((orow >> 2) & 3)) * 8)] = v;
    }
}

// ---------------------------------------------------------------------------
// Kernel 2: flash attention + fused output projection.
// Value-producing math VERBATIM r9/r10 (validated). NEW: cross-window
// software pipeline with 1 barrier/window: K staged 2-ahead (4 buffers),
// V 1-ahead (2 buffers). Phase t: stage K(t+2),V(t+1); QK(t+1) -> next
// (independent MFMA, overlaps softmax(t) VALU); softmax+PV(t); barrier.
// All buffer indices fold to compile-time under unroll-4.
// ---------------------------------------------------------------------------
__global__ __launch_bounds__(256, 3) void flash_kernel(
    const unsigned short* __restrict__ gQ,
    const unsigned short* __restrict__ gK,
    const unsigned short* __restrict__ gVt,
    const float* __restrict__ Wo, const float* __restrict__ bo,
    float* __restrict__ out)
{
    __shared__ unsigned short kbuf[4][4096];   // 4 x [64 keys][64 d]  (32 KB)
    __shared__ unsigned short vbuf[2][4096];   // 2 x [2 sub][32k x 64d] (16 KB)

    const int bh = blockIdx.x, h = bh & (Hn - 1), b = bh >> 4;
    const int tid = threadIdx.x;
    const int w = tid >> 6, lane = tid & 63;
    const int l31 = lane & 31, l5 = lane >> 5;
    const int qrow = blockIdx.y * 128 + w * 32 + l31;

    bf16x8 qf[4];
#pragma unroll
    for (int kk = 0; kk < 4; ++kk)
        qf[kk] = *(const bf16x8*)&gQ[((size_t)bh * Nseq + qrow) * Dh + kk * 16 + l5 * 8];

    // per-lane LDS read bases (swizzles invariant: 32 % 8 == 0)
    const unsigned short* kbase[4];
#pragma unroll
    for (int kk = 0; kk < 4; ++kk)
        kbase[kk] = &kbuf[0][l31 * 64 + (((kk * 2 + l5) ^ (l31 & 7)) * 8)];
    const unsigned short* vbase[2];
#pragma unroll
    for (int ks = 0; ks < 2; ++ks)
        vbase[ks] = &vbuf[0][l31 * 32 + (((ks * 2 + l5) ^ ((l31 >> 2) & 3)) * 8)];

    float z0 = 0.f;
    asm volatile("" : "+v"(z0));
    f32x16 zc = {z0, z0, z0, z0, z0, z0, z0, z0, z0, z0, z0, z0, z0, z0, z0, z0};

    f32x16 acc[2] = {};            // O^T: rows d, col q = l31
    float l = 0.f;

    auto stageK = [&](int t, int slot) {
        const unsigned short* ks = gK + ((size_t)bh * Nseq + (size_t)t * 64) * Dh;
#pragma unroll
        for (int i = 0; i < 2; ++i) {
            int off = w * 1024 + i * 512 + lane * 8;
            __builtin_amdgcn_global_load_lds((const AS1 void*)(ks + off),
                                             (AS3 void*)(&kbuf[slot][w * 1024 + i * 512]), 16, 0, 0);
        }
    };
    auto stageV = [&](int t, int slot) {
        const unsigned short* vs = gVt + ((size_t)(bh * NT32 + 2 * t)) * 2048;
#pragma unroll
        for (int i = 0; i < 2; ++i) {
            int off = w * 1024 + i * 512 + lane * 8;
            __builtin_amdgcn_global_load_lds((const AS1 void*)(vs + off),
                                             (AS3 void*)(&vbuf[slot][w * 1024 + i * 512]), 16, 0, 0);
        }
    };

    // one 32-key subtile of QK^T (r9-verbatim MFMA chain)
    auto qk_sub = [&](const int slot, const int sub) -> f32x16 {
        const int o = slot * 4096 + sub * 2048;
        bf16x8 kf = *(const bf16x8*)(kbase[0] + o);
        f32x16 s = MFMA32(kf, qf[0], zc, 0, 0, 0);
        kf = *(const bf16x8*)(kbase[1] + o);
        s = MFMA32(kf, qf[1], s, 0, 0, 0);
        kf = *(const bf16x8*)(kbase[2] + o);
        s = MFMA32(kf, qf[2], s, 0, 0, 0);
        kf = *(const bf16x8*)(kbase[3] + o);
        s = MFMA32(kf, qf[3], s, 0, 0, 0);
        return s;
    };

    // r9-verbatim softmax + PV for one subtile
    auto soft_pv = [&](f32x16& s, const int sub, const int vslot) {
#pragma unroll
        for (int r = 0; r < 16; ++r) s[r] = exp2v(s[r]);
        f32x2* sp = (f32x2*)&s;
        f32x2 u0 = pk_add(sp[0], sp[1]), u1 = pk_add(sp[2], sp[3]);
        f32x2 u2 = pk_add(sp[4], sp[5]), u3 = pk_add(sp[6], sp[7]);
        u0 = pk_add(u0, u1); u2 = pk_add(u2, u3);
        u0 = pk_add(u0, u2);
        l += u0[0] + u0[1];
#pragma unroll
        for (int ks = 0; ks < 2; ++ks) {
            const int b0 = 8 * ks;
            unsigned x0 = cvt_pk_bf16(s[b0 + 0], s[b0 + 1]);
            unsigned x1 = cvt_pk_bf16(s[b0 + 2], s[b0 + 3]);
            unsigned y0 = cvt_pk_bf16(s[b0 + 4], s[b0 + 5]);
            unsigned y1 = cvt_pk_bf16(s[b0 + 6], s[b0 + 7]);
            swap32(x0, y0);
            swap32(x1, y1);
            bf16x8 pf;
            ((unsigned*)&pf)[0] = x0; ((unsigned*)&pf)[1] = x1;
            ((unsigned*)&pf)[2] = y0; ((unsigned*)&pf)[3] = y1;
#pragma unroll
            for (int dt = 0; dt < 2; ++dt) {
                bf16x8 vf = *(const bf16x8*)(vbase[ks] + dt * 1024 + sub * 2048 + vslot * 4096);
                acc[dt] = MFMA32(vf, pf, acc[dt], 0, 0, 0);
            }
        }
    };

    // ---- prologue: K0->kb0, V0->vb0, K1->kb1; S(0) ----
    stageK(0, 0);
    stageV(0, 0);
    stageK(1, 1);
    __syncthreads();
    f32x16 sA = qk_sub(0, 0);
    f32x16 sB = qk_sub(0, 1);

    // ---- 32 phases, 1 barrier each; all slot indices compile-time ----
#pragma unroll 1
    for (int t4 = 0; t4 < NT64; t4 += 4) {
#pragma unroll
        for (int u = 0; u < 4; ++u) {
            const int t = t4 + u;
            stageK(min(t + 2, NT64 - 1), (u + 2) & 3);   // 2-ahead
            stageV(min(t + 1, NT64 - 1), (u + 1) & 1);   // 1-ahead
            f32x16 nA = qk_sub((u + 1) & 3, 0);          // QK(t+1) subtile A
            soft_pv(sA, 0, u & 1);                       // softmax+PV(t) A
            f32x16 nB = qk_sub((u + 1) & 3, 1);          // QK(t+1) subtile B
            soft_pv(sB, 1, u & 1);                       // softmax+PV(t) B
            sA = nA; sB = nB;
            __syncthreads();
        }
    }
    // (last phase computes one discarded S from duplicate-staged K31 — finite, unused)

    // ---- epilogue: stage Wo^T (bf16, swizzled) into kbuf[0] ----
    {
        unsigned short* wl = &kbuf[0][0];
        for (int c = tid; c < 512; c += 256) {
            int o = c >> 3, c8 = c & 7;
            int cc = ((c8 ^ (o & 7)) * 8);
#pragma unroll
            for (int jj = 0; jj < 4; ++jj) wl[o * 64 + cc + jj]     = f2bf(Wo[(h * 64 + c8 * 8 + jj) * 64 + o]);
#pragma unroll
            for (int jj = 0; jj < 4; ++jj) wl[o * 64 + cc + 4 + jj] = f2bf(Wo[(h * 64 + c8 * 8 + 4 + jj) * 64 + o]);
        }
    }
    __syncthreads();

    l += __shfl_xor(l, 32);
    float inv = 1.f / l;
#pragma unroll
    for (int dt = 0; dt < 2; ++dt)
#pragma unroll
        for (int r = 0; r < 16; ++r) acc[dt][r] *= inv;

    f32x16 oc[2] = {};
#pragma unroll
    for (int kk = 0; kk < 4; ++kk) {
        const int dt = kk >> 1;
        const int b0 = 8 * (kk & 1);
        unsigned x0 = cvt_pk_bf16(acc[dt][b0 + 0], acc[dt][b0 + 1]);
        unsigned x1 = cvt_pk_bf16(acc[dt][b0 + 2], acc[dt][b0 + 3]);
        unsigned y0 = cvt_pk_bf16(acc[dt][b0 + 4], acc[dt][b0 + 5]);
        unsigned y1 = cvt_pk_bf16(acc[dt][b0 + 6], acc[dt][b0 + 7]);
        swap32(x0, y0);
        swap32(x1, y1);
        bf16x8 af;
        ((unsigned*)&af)[0] = x0; ((unsigned*)&af)[1] = x1;
        ((unsigned*)&af)[2] = y0; ((unsigned*)&af)[3] = y1;
#pragma unroll
        for (int ot = 0; ot < 2; ++ot) {
            bf16x8 wf = *(const bf16x8*)(kbase[kk] + ot * 2048);   // kbuf[0] holds Wo^T
            oc[ot] = MFMA32(wf, af, oc[ot], 0, 0, 0);
        }
    }

    float* obase = out + (((size_t)b * Nseq + qrow) * Hn + h) * Dh;
#pragma unroll
    for (int ot = 0; ot < 2; ++ot)
#pragma unroll
        for (int rq = 0; rq < 4; ++rq) {
            int o = ot * 32 + rq * 8 + l5 * 4;
            f32x4 bb = *(const f32x4*)&bo[h * 64 + o];
            f32x4 vv;
            vv[0] = oc[ot][rq * 4 + 0] + bb[0];
            vv[1] = oc[ot][rq * 4 + 1] + bb[1];
            vv[2] = oc[ot][rq * 4 + 2] + bb[2];
            vv[3] = oc[ot][rq * 4 + 3] + bb[3];
            *(f32x4*)&obase[o] = vv;
        }
}

extern "C" void kernel_launch(void* const* d_in, const int* in_sizes, int n_in,
                              void* d_out, int out_size, void* d_ws, size_t ws_size,
                              hipStream_t stream) {
    const float* x  = (const float*)d_in[0];
    const float* Wq = (const float*)d_in[1];
    const float* bq = (const float*)d_in[2];
    const float* Wk = (const float*)d_in[3];
    const float* bk = (const float*)d_in[4];
    const float* Wv = (const float*)d_in[5];
    const float* bv = (const float*)d_in[6];
    const float* Wo = (const float*)d_in[7];
    const float* bo = (const float*)d_in[8];
    float* out = (float*)d_out;

    unsigned short* gQ   = (unsigned short*)d_ws;
    unsigned short* gK   = gQ + (size_t)BH * Nseq * Dh;
    unsigned short* gVt  = gK + (size_t)BH * Nseq * Dh;
    unsigned short* gWtH = gVt + (size_t)BH * Nseq * Dh;
    unsigned short* gWtL = gWtH + (size_t)3 * 16 * 64 * 64;

    wprep_kernel<<<48, 256, 0, stream>>>(Wq, Wk, Wv, gWtH, gWtL);
    proj_kernel<<<dim3(BH, Nseq / 64), 256, 0, stream>>>(x, gWtH, gWtL, bq, bk, bv, gQ, gK, gVt);
    flash_kernel<<<dim3(BH, Nseq / 128), 256, 0, stream>>>(gQ, gK, gVt, Wo, bo, out);
}

// Round 14
// 115.607 us; speedup vs baseline: 1.1549x; 1.1549x over previous
//
#include <hip/hip_runtime.h>

#define Bsz  4
#define Nseq 2048
#define Hn   16
#define Dh   64
#define BH   (Bsz*Hn)
#define NT64 (Nseq/64)
#define NT32 (Nseq/32)

#define AS1 __attribute__((address_space(1)))
#define AS3 __attribute__((address_space(3)))

typedef __attribute__((ext_vector_type(8))) short bf16x8;
typedef __attribute__((ext_vector_type(16))) float f32x16;
typedef __attribute__((ext_vector_type(4))) float f32x4;
typedef __attribute__((ext_vector_type(2))) float f32x2;

#define MFMA32 __builtin_amdgcn_mfma_f32_32x32x16_bf16

static __device__ __forceinline__ unsigned short f2bf(float f) {
    unsigned u = __float_as_uint(f);
    u = (u + 0x7fffu + ((u >> 16) & 1u)) >> 16;
    return (unsigned short)u;
}
static __device__ __forceinline__ float bf2f(unsigned short s) {
    return __uint_as_float((unsigned)s << 16);
}
static __device__ __forceinline__ unsigned cvt_pk_bf16(float lo, float hi) {
    unsigned r;
    asm("v_cvt_pk_bf16_f32 %0, %1, %2" : "=v"(r) : "v"(lo), "v"(hi));
    return r;
}
static __device__ __forceinline__ void swap32(unsigned &a, unsigned &b) {
    asm("v_permlane32_swap_b32 %0, %1" : "+v"(a), "+v"(b));
}
static __device__ __forceinline__ float exp2v(float x) {
    float r;
    asm("v_exp_f32 %0, %1" : "=v"(r) : "v"(x));
    return r;
}
static __device__ __forceinline__ f32x2 pk_add(f32x2 a, f32x2 b) {
    f32x2 d;
    asm("v_pk_add_f32 %0, %1, %2" : "=v"(d) : "v"(a), "v"(b));
    return d;
}

// ---------------------------------------------------------------------------
// Kernel 1: QKV projections via bf16 MFMA with hi/lo split precision.
// Inline scalar W loads (r5/r6-validated), direct stores, no wprep.
//   gQ : [BH][N][64]                pre-scaled by log2(e)/32
//   gK : [BH][N][64]                16B-chunk swizzle: chunk ^= (n&7)
//   gVt: [BH][NT32][64 o][32 n]     per-32-key tile transposed,
//                                   8-key chunk swizzle: chunk ^= (o>>2)&3
// ---------------------------------------------------------------------------
__global__ __launch_bounds__(256) void proj_kernel(
    const float* __restrict__ x,
    const float* __restrict__ Wq, const float* __restrict__ bq,
    const float* __restrict__ Wk, const float* __restrict__ bk,
    const float* __restrict__ Wv, const float* __restrict__ bv,
    unsigned short* __restrict__ gQ, unsigned short* __restrict__ gK,
    unsigned short* __restrict__ gVt)
{
    const int bh = blockIdx.x, h = bh & (Hn - 1), b = bh >> 4;
    const int n0 = blockIdx.y * 64;
    const int tid = threadIdx.x;
    const int w = tid >> 6, lane = tid & 63, l31 = lane & 31, l5 = lane >> 5;
    const int qi = w >> 1, oj = w & 1;

    const int nrow = n0 + qi * 32 + l31;
    const float* xrow = x + (((size_t)b * Nseq + nrow) * Hn + h) * Dh;

    bf16x8 xh[4], xl[4];
#pragma unroll
    for (int ks = 0; ks < 4; ++ks) {
        f32x4 v0 = *(const f32x4*)&xrow[ks * 16 + l5 * 8];
        f32x4 v1 = *(const f32x4*)&xrow[ks * 16 + l5 * 8 + 4];
#pragma unroll
        for (int e = 0; e < 4; ++e) {
            unsigned short h0 = f2bf(v0[e]);
            xh[ks][e] = (short)h0;
            xl[ks][e] = (short)f2bf(v0[e] - bf2f(h0));
            unsigned short h1 = f2bf(v1[e]);
            xh[ks][4 + e] = (short)h1;
            xl[ks][4 + e] = (short)f2bf(v1[e] - bf2f(h1));
        }
    }

    const int o = oj * 32 + l31;
    const float* Wm[3] = {Wq, Wk, Wv};

    f32x16 acc[3] = {};
#pragma unroll
    for (int m = 0; m < 3; ++m) {
        const float* Wb = Wm[m] + h * 4096 + o;
#pragma unroll
        for (int ks = 0; ks < 4; ++ks) {
            bf16x8 wh, wl;
#pragma unroll
            for (int e = 0; e < 8; ++e) {
                float wv = Wb[(ks * 16 + l5 * 8 + e) * 64];
                unsigned short hh = f2bf(wv);
                wh[e] = (short)hh;
                wl[e] = (short)f2bf(wv - bf2f(hh));
            }
            if (m < 2) {
                acc[m] = MFMA32(xh[ks], wh, acc[m], 0, 0, 0);
                acc[m] = MFMA32(xl[ks], wh, acc[m], 0, 0, 0);
                acc[m] = MFMA32(xh[ks], wl, acc[m], 0, 0, 0);
            } else {               // V transposed: A = W^T, B = x^T
                acc[2] = MFMA32(wh, xh[ks], acc[2], 0, 0, 0);
                acc[2] = MFMA32(wl, xh[ks], acc[2], 0, 0, 0);
                acc[2] = MFMA32(wh, xl[ks], acc[2], 0, 0, 0);
            }
        }
    }

    {   // Q store (pre-scaled by log2e/32)
        float bias = bq[h * 64 + o];
#pragma unroll
        for (int r = 0; r < 16; ++r) {
            int nl = (r & 3) + 8 * (r >> 2) + 4 * l5;
            int n = n0 + qi * 32 + nl;
            gQ[((size_t)bh * Nseq + n) * Dh + o] =
                f2bf((acc[0][r] + bias) * 0.0450842200f);
        }
    }
    {   // K store (chunk-swizzled rows)
        float bias = bk[h * 64 + o];
#pragma unroll
        for (int r = 0; r < 16; ++r) {
            int nl = (r & 3) + 8 * (r >> 2) + 4 * l5;
            int n = n0 + qi * 32 + nl;
            int c = (((o >> 3) ^ (n & 7)) * 8) + (o & 7);
            gK[((size_t)bh * Nseq + n) * Dh + c] = f2bf(acc[1][r] + bias);
        }
    }
    {   // V store: acc rows = o, cols = n; per-32-key tile, chunk ^= (o>>2)&3
        const int tile = (n0 >> 5) + qi;
        const int kt = l31;
#pragma unroll
        for (int r = 0; r < 16; ++r) {
            int ol = (r & 3) + 8 * (r >> 2) + 4 * l5;
            int ov = oj * 32 + ol;
            float bias = bv[h * 64 + ov];
            int c = (((kt >> 3) ^ ((ov >> 2) & 3)) * 8) + (kt & 7);
            gVt[(((size_t)bh * NT32 + tile) * 64 + ov) * 32 + c] =
                f2bf(acc[2][r] + bias);
        }
    }
}

// ---------------------------------------------------------------------------
// Kernel 2: flash attention + fused output projection.
// VERBATIM round-9 kernel (validated: passed, absmax 1.95e-3, 85.2 us).
// Wave owns 32 q-rows; 64-key windows; two 32-key subtiles per barrier
// window; K+V double-buffered via global_load_lds.
// ---------------------------------------------------------------------------
__global__ __launch_bounds__(256, 4) void flash_kernel(
    const unsigned short* __restrict__ gQ,
    const unsigned short* __restrict__ gK,
    const unsigned short* __restrict__ gVt,
    const float* __restrict__ Wo, const float* __restrict__ bo,
    float* __restrict__ out)
{
    __shared__ unsigned short kbuf[2][4096];   // [buf][64 keys][64 d]
    __shared__ unsigned short vbuf[2][4096];   // [buf][2 subtiles][64 d][32 k]

    const int bh = blockIdx.x, h = bh & (Hn - 1), b = bh >> 4;
    const int tid = threadIdx.x;
    const int w = tid >> 6, lane = tid & 63;
    const int l31 = lane & 31, l5 = lane >> 5;
    const int qrow = blockIdx.y * 128 + w * 32 + l31;

    bf16x8 qf[4];
#pragma unroll
    for (int kk = 0; kk < 4; ++kk)
        qf[kk] = *(const bf16x8*)&gQ[((size_t)bh * Nseq + qrow) * Dh + kk * 16 + l5 * 8];

    float z0 = 0.f;
    asm volatile("" : "+v"(z0));
    f32x16 zc = {z0, z0, z0, z0, z0, z0, z0, z0, z0, z0, z0, z0, z0, z0, z0, z0};

    f32x16 acc[2] = {};            // O^T: rows d, col q = l31
    float l = 0.f;

    auto stage = [&](int t, int bufi) {   // stage one 64-key window (K + V)
        const unsigned short* ks = gK + ((size_t)bh * Nseq + (size_t)t * 64) * Dh;
        const unsigned short* vs = gVt + ((size_t)(bh * NT32 + 2 * t)) * 2048;
#pragma unroll
        for (int i = 0; i < 2; ++i) {
            int off = w * 1024 + i * 512 + lane * 8;
            __builtin_amdgcn_global_load_lds((const AS1 void*)(ks + off),
                                             (AS3 void*)(&kbuf[bufi][w * 1024 + i * 512]), 16, 0, 0);
            __builtin_amdgcn_global_load_lds((const AS1 void*)(vs + off),
                                             (AS3 void*)(&vbuf[bufi][w * 1024 + i * 512]), 16, 0, 0);
        }
    };

    // qk_tile (kb points at a 32-key subtile, rows = l31)
    auto qk_tile = [&](const unsigned short* __restrict__ kb) -> f32x16 {
        const int roff = l31 * 64;
        const int sw = l31 & 7;
        bf16x8 kf = *(const bf16x8*)&kb[roff + ((l5 ^ sw) * 8)];
        f32x16 s = MFMA32(kf, qf[0], zc, 0, 0, 0);
#pragma unroll
        for (int kk = 1; kk < 4; ++kk) {
            kf = *(const bf16x8*)&kb[roff + (((kk * 2 + l5) ^ sw) * 8)];
            s = MFMA32(kf, qf[kk], s, 0, 0, 0);
        }
        return s;
    };

    // softmax + PV (vb points at a 32-key subtile [64 d][32 k])
    auto soft_pv = [&](f32x16& s, const unsigned short* __restrict__ vb) {
#pragma unroll
        for (int r = 0; r < 16; ++r) s[r] = exp2v(s[r]);
        f32x2* sp = (f32x2*)&s;
        f32x2 u0 = pk_add(sp[0], sp[1]), u1 = pk_add(sp[2], sp[3]);
        f32x2 u2 = pk_add(sp[4], sp[5]), u3 = pk_add(sp[6], sp[7]);
        u0 = pk_add(u0, u1); u2 = pk_add(u2, u3);
        u0 = pk_add(u0, u2);
        l += u0[0] + u0[1];
#pragma unroll
        for (int ks = 0; ks < 2; ++ks) {
            const int b0 = 8 * ks;
            unsigned x0 = cvt_pk_bf16(s[b0 + 0], s[b0 + 1]);
            unsigned x1 = cvt_pk_bf16(s[b0 + 2], s[b0 + 3]);
            unsigned y0 = cvt_pk_bf16(s[b0 + 4], s[b0 + 5]);
            unsigned y1 = cvt_pk_bf16(s[b0 + 6], s[b0 + 7]);
            swap32(x0, y0);
            swap32(x1, y1);
            bf16x8 pf;
            ((unsigned*)&pf)[0] = x0; ((unsigned*)&pf)[1] = x1;
            ((unsigned*)&pf)[2] = y0; ((unsigned*)&pf)[3] = y1;
#pragma unroll
            for (int dt = 0; dt < 2; ++dt) {
                const int row = dt * 32 + l31;
                bf16x8 vf = *(const bf16x8*)&vb[row * 32 + (((ks * 2 + l5) ^ ((row >> 2) & 3)) * 8)];
                acc[dt] = MFMA32(vf, pf, acc[dt], 0, 0, 0);
            }
        }
    };

    auto window_step = [&](const unsigned short* __restrict__ kb,
                           const unsigned short* __restrict__ vb) {
        f32x16 sA = qk_tile(kb);          // subtile 0 (keys 0-31 of window)
        f32x16 sB = qk_tile(kb + 2048);   // subtile 1 — issued early for overlap
        soft_pv(sA, vb);                  // l/acc order: subtile 0 first
        soft_pv(sB, vb + 2048);
    };

    stage(0, 0);

#pragma unroll 1
    for (int t2 = 0; t2 < NT64; t2 += 2) {
        __syncthreads();                   // buf0 ready (vmcnt drained)
        stage(t2 + 1, 1);                  // t2+1 <= NT64-1 always
        window_step(&kbuf[0][0], &vbuf[0][0]);
        __syncthreads();                   // buf1 ready
        if (t2 + 2 < NT64) stage(t2 + 2, 0);
        window_step(&kbuf[1][0], &vbuf[1][0]);
    }

    // ---- epilogue: stage Wo^T (bf16, swizzled) into kbuf[0] ----
    __syncthreads();
    {
        unsigned short* wl = &kbuf[0][0];
        for (int c = tid; c < 512; c += 256) {
            int o = c >> 3, c8 = c & 7;
            int cc = ((c8 ^ (o & 7)) * 8);
#pragma unroll
            for (int jj = 0; jj < 4; ++jj) wl[o * 64 + cc + jj]     = f2bf(Wo[(h * 64 + c8 * 8 + jj) * 64 + o]);
#pragma unroll
            for (int jj = 0; jj < 4; ++jj) wl[o * 64 + cc + 4 + jj] = f2bf(Wo[(h * 64 + c8 * 8 + 4 + jj) * 64 + o]);
        }
    }
    __syncthreads();

    l += __shfl_xor(l, 32);
    float inv = 1.f / l;
#pragma unroll
    for (int dt = 0; dt < 2; ++dt)
#pragma unroll
        for (int r = 0; r < 16; ++r) acc[dt][r] *= inv;

    const unsigned short* wot = &kbuf[0][0];
    f32x16 oc[2] = {};
#pragma unroll
    for (int kk = 0; kk < 4; ++kk) {
        const int dt = kk >> 1;
        const int b0 = 8 * (kk & 1);
        unsigned x0 = cvt_pk_bf16(acc[dt][b0 + 0], acc[dt][b0 + 1]);
        unsigned x1 = cvt_pk_bf16(acc[dt][b0 + 2], acc[dt][b0 + 3]);
        unsigned y0 = cvt_pk_bf16(acc[dt][b0 + 4], acc[dt][b0 + 5]);
        unsigned y1 = cvt_pk_bf16(acc[dt][b0 + 6], acc[dt][b0 + 7]);
        swap32(x0, y0);
        swap32(x1, y1);
        bf16x8 af;
        ((unsigned*)&af)[0] = x0; ((unsigned*)&af)[1] = x1;
        ((unsigned*)&af)[2] = y0; ((unsigned*)&af)[3] = y1;
#pragma unroll
        for (int ot = 0; ot < 2; ++ot) {
            int row = ot * 32 + l31;
            bf16x8 wf = *(const bf16x8*)&wot[row * 64 + (((kk * 2 + l5) ^ (row & 7)) * 8)];
            oc[ot] = MFMA32(wf, af, oc[ot], 0, 0, 0);
        }
    }

    float* obase = out + (((size_t)b * Nseq + qrow) * Hn + h) * Dh;
#pragma unroll
    for (int ot = 0; ot < 2; ++ot)
#pragma unroll
        for (int rq = 0; rq < 4; ++rq) {
            int o = ot * 32 + rq * 8 + l5 * 4;
            f32x4 bb = *(const f32x4*)&bo[h * 64 + o];
            f32x4 vv;
            vv[0] = oc[ot][rq * 4 + 0] + bb[0];
            vv[1] = oc[ot][rq * 4 + 1] + bb[1];
            vv[2] = oc[ot][rq * 4 + 2] + bb[2];
            vv[3] = oc[ot][rq * 4 + 3] + bb[3];
            *(f32x4*)&obase[o] = vv;
        }
}

extern "C" void kernel_launch(void* const* d_in, const int* in_sizes, int n_in,
                              void* d_out, int out_size, void* d_ws, size_t ws_size,
                              hipStream_t stream) {
    const float* x  = (const float*)d_in[0];
    const float* Wq = (const float*)d_in[1];
    const float* bq = (const float*)d_in[2];
    const float* Wk = (const float*)d_in[3];
    const float* bk = (const float*)d_in[4];
    const float* Wv = (const float*)d_in[5];
    const float* bv = (const float*)d_in[6];
    const float* Wo = (const float*)d_in[7];
    const float* bo = (const float*)d_in[8];
    float* out = (float*)d_out;

    unsigned short* gQ  = (unsigned short*)d_ws;
    unsigned short* gK  = gQ + (size_t)BH * Nseq * Dh;
    unsigned short* gVt = gK + (size_t)BH * Nseq * Dh;

    proj_kernel<<<dim3(BH, Nseq / 64), 256, 0, stream>>>(x, Wq, bq, Wk, bk, Wv, bv, gQ, gK, gVt);
    flash_kernel<<<dim3(BH, Nseq / 128), 256, 0, stream>>>(gQ, gK, gVt, Wo, bo, out);
}